// Round 1
// baseline (2280.747 us; speedup 1.0000x reference)
//
#include <hip/hip_runtime.h>
#include <math.h>

#define LSTRIDE 128

__device__ __forceinline__ float silu_f(float v) {
    return v / (1.0f + __expf(-v));
}

// swizzled column index: XOR row-group into bits >=3 of column, bijective per row,
// preserves float4 (16B) contiguity since bits 0..2 untouched.
__device__ __forceinline__ int swzc(int e, int c) { return c ^ (((e) >> 2) << 3); }

// ---------------------------------------------------------------------------
// Tile matvec: 64 edges x N outputs, input in LDS A (swizzled, stride LSTRIDE),
// W row-major [K][N] in global. 256 threads: es = tid>>4 (edge slot, 4 edges),
// cs = tid&15 (col slot, CW cols). acc must have 4*CW floats.
// ---------------------------------------------------------------------------
template<int K, int N>
__device__ __forceinline__ void mv_tile(const float* __restrict__ W,
                                        const float* __restrict__ A,
                                        int es, int cs, float* __restrict__ acc) {
    constexpr int CW = N / 16;
    const int swz = es << 3;
    const int r0 = es * 4;
#pragma unroll
    for (int q = 0; q < 4 * CW; ++q) acc[q] = 0.0f;
    for (int kb = 0; kb < K; kb += 8) {
        const int ka = kb ^ swz;
        float4 h0a = *(const float4*)&A[(r0 + 0) * LSTRIDE + ka];
        float4 h0b = *(const float4*)&A[(r0 + 0) * LSTRIDE + ka + 4];
        float4 h1a = *(const float4*)&A[(r0 + 1) * LSTRIDE + ka];
        float4 h1b = *(const float4*)&A[(r0 + 1) * LSTRIDE + ka + 4];
        float4 h2a = *(const float4*)&A[(r0 + 2) * LSTRIDE + ka];
        float4 h2b = *(const float4*)&A[(r0 + 2) * LSTRIDE + ka + 4];
        float4 h3a = *(const float4*)&A[(r0 + 3) * LSTRIDE + ka];
        float4 h3b = *(const float4*)&A[(r0 + 3) * LSTRIDE + ka + 4];
#pragma unroll
        for (int ki = 0; ki < 8; ++ki) {
            const float* wr = W + (size_t)(kb + ki) * N + cs * CW;
            float w[CW];
#pragma unroll
            for (int i = 0; i < CW; ++i) w[i] = wr[i];
            float hv0, hv1, hv2, hv3;
            switch (ki) {
                case 0: hv0 = h0a.x; hv1 = h1a.x; hv2 = h2a.x; hv3 = h3a.x; break;
                case 1: hv0 = h0a.y; hv1 = h1a.y; hv2 = h2a.y; hv3 = h3a.y; break;
                case 2: hv0 = h0a.z; hv1 = h1a.z; hv2 = h2a.z; hv3 = h3a.z; break;
                case 3: hv0 = h0a.w; hv1 = h1a.w; hv2 = h2a.w; hv3 = h3a.w; break;
                case 4: hv0 = h0b.x; hv1 = h1b.x; hv2 = h2b.x; hv3 = h3b.x; break;
                case 5: hv0 = h0b.y; hv1 = h1b.y; hv2 = h2b.y; hv3 = h3b.y; break;
                case 6: hv0 = h0b.z; hv1 = h1b.z; hv2 = h2b.z; hv3 = h3b.z; break;
                default: hv0 = h0b.w; hv1 = h1b.w; hv2 = h2b.w; hv3 = h3b.w; break;
            }
#pragma unroll
            for (int i = 0; i < CW; ++i) {
                acc[0 * CW + i] = fmaf(hv0, w[i], acc[0 * CW + i]);
                acc[1 * CW + i] = fmaf(hv1, w[i], acc[1 * CW + i]);
                acc[2 * CW + i] = fmaf(hv2, w[i], acc[2 * CW + i]);
                acc[3 * CW + i] = fmaf(hv3, w[i], acc[3 * CW + i]);
            }
        }
    }
}

// load a 64-row tile (cols multiple of 4) from global into LDS with swizzle; zero-fills invalid rows
__device__ __forceinline__ void load_tile(const float* __restrict__ g, float* __restrict__ A,
                                          int rows, int cols, long e0, int gstride, int tid) {
    const int quads = cols >> 2;
    for (int idx = tid; idx < 64 * quads; idx += 256) {
        int r = idx / quads, q = idx - r * quads;
        float4 v = make_float4(0.f, 0.f, 0.f, 0.f);
        if (r < rows) v = *(const float4*)&g[(e0 + r) * (size_t)gstride + q * 4];
        *(float4*)&A[r * LSTRIDE + swzc(r, q * 4)] = v;
    }
}

__device__ __forceinline__ void store_silu_bias(float* __restrict__ dst, const float* acc,
                                                const float* __restrict__ bias, int es, int cs) {
    float bv[8];
#pragma unroll
    for (int i = 0; i < 8; ++i) bv[i] = bias[cs * 8 + i];
#pragma unroll
    for (int j = 0; j < 4; ++j) {
        int e = es * 4 + j;
        int cb = swzc(e, cs * 8);
        float tmp[8];
#pragma unroll
        for (int i = 0; i < 8; ++i) tmp[i] = silu_f(acc[j * 8 + i] + bv[i]);
        *(float4*)&dst[e * LSTRIDE + cb]     = *(float4*)&tmp[0];
        *(float4*)&dst[e * LSTRIDE + cb + 4] = *(float4*)&tmp[4];
    }
}

__device__ __forceinline__ void add_silu_bias(float* __restrict__ dst, const float* acc,
                                              const float* __restrict__ bias, int es, int cs) {
    float bv[8];
#pragma unroll
    for (int i = 0; i < 8; ++i) bv[i] = bias[cs * 8 + i];
#pragma unroll
    for (int j = 0; j < 4; ++j) {
        int e = es * 4 + j;
        int cb = swzc(e, cs * 8);
        float4 v0 = *(const float4*)&dst[e * LSTRIDE + cb];
        float4 v1 = *(const float4*)&dst[e * LSTRIDE + cb + 4];
        float tmp[8] = {v0.x, v0.y, v0.z, v0.w, v1.x, v1.y, v1.z, v1.w};
#pragma unroll
        for (int i = 0; i < 8; ++i) tmp[i] += silu_f(acc[j * 8 + i] + bv[i]);
        *(float4*)&dst[e * LSTRIDE + cb]     = *(float4*)&tmp[0];
        *(float4*)&dst[e * LSTRIDE + cb + 4] = *(float4*)&tmp[4];
    }
}

// ---------------------------------------------------------------------------
// combine small basis weights: wc_rbf[6][128] = W_rbf1@W_rbf2, wc_sbf[42][64]
// ---------------------------------------------------------------------------
__global__ void kweights(const float* __restrict__ W_rbf1, const float* __restrict__ W_rbf2,
                         const float* __restrict__ W_sbf1, const float* __restrict__ W_sbf2,
                         float* __restrict__ wc_rbf, float* __restrict__ wc_sbf) {
    int tid = blockIdx.x * blockDim.x + threadIdx.x;
    int nt = blockDim.x * gridDim.x;
    for (int idx = tid; idx < 6 * 128; idx += nt) {
        int r = idx / 128, c = idx - r * 128;
        float s = 0.f;
#pragma unroll
        for (int b = 0; b < 8; ++b) s += W_rbf1[r * 8 + b] * W_rbf2[b * 128 + c];
        wc_rbf[idx] = s;
    }
    for (int idx = tid; idx < 42 * 64; idx += nt) {
        int r = idx / 64, c = idx - r * 64;
        float s = 0.f;
#pragma unroll
        for (int b = 0; b < 8; ++b) s += W_sbf1[r * 8 + b] * W_sbf2[b * 64 + c];
        wc_sbf[idx] = s;
    }
}

// ---------------------------------------------------------------------------
// pre phase: x_kd = silu( (silu(x@W_kj+b_kj) * (rbf@Wc_rbf)) @ W_down )  [E,64]
// ---------------------------------------------------------------------------
__global__ __launch_bounds__(256, 2) void kedge_pre(
        const float* __restrict__ x, const float* __restrict__ rbf,
        const float* __restrict__ W_kj, const float* __restrict__ b_kj,
        const float* __restrict__ wc_rbf, const float* __restrict__ W_down,
        float* __restrict__ xkd, int E) {
    __shared__ float A[64 * LSTRIDE];
    __shared__ float Bt[64 * LSTRIDE];
    const int tid = threadIdx.x;
    const int es = tid >> 4, cs = tid & 15;
    const long e0 = (long)blockIdx.x * 64;
    long rem = (long)E - e0;
    const int rows = rem > 64 ? 64 : (int)rem;

    load_tile(x, A, rows, 128, e0, 128, tid);
    __syncthreads();

    float acc[32];
    mv_tile<128, 128>(W_kj, A, es, cs, acc);
    __syncthreads();   // done reading A; reuse its space for wcr + rbf tile

    float* wcr = A;            // 768 floats
    float* rbt = A + 768;      // 64*6 floats
    for (int idx = tid; idx < 768; idx += 256) wcr[idx] = wc_rbf[idx];
    for (int idx = tid; idx < 64 * 6; idx += 256) {
        int r = idx / 6, s = idx - r * 6;
        rbt[idx] = (r < rows) ? rbf[(e0 + r) * 6 + s] : 0.f;
    }
    __syncthreads();

    {
        float bv[8];
#pragma unroll
        for (int i = 0; i < 8; ++i) bv[i] = b_kj[cs * 8 + i];
#pragma unroll
        for (int j = 0; j < 4; ++j) {
            int e = es * 4 + j;
            int cb = swzc(e, cs * 8);
            float rv[6];
#pragma unroll
            for (int s = 0; s < 6; ++s) rv[s] = rbt[e * 6 + s];
            float tmp[8];
#pragma unroll
            for (int i = 0; i < 8; ++i) {
                int c = cs * 8 + i;
                float v = silu_f(acc[j * 8 + i] + bv[i]);
                float re = 0.f;
#pragma unroll
                for (int s = 0; s < 6; ++s) re = fmaf(rv[s], wcr[s * 128 + c], re);
                tmp[i] = v * re;
            }
            *(float4*)&Bt[e * LSTRIDE + cb]     = *(float4*)&tmp[0];
            *(float4*)&Bt[e * LSTRIDE + cb + 4] = *(float4*)&tmp[4];
        }
    }
    __syncthreads();

    float acc2[16];
    mv_tile<128, 64>(W_down, Bt, es, cs, acc2);
#pragma unroll
    for (int j = 0; j < 4; ++j) {
        int e = es * 4 + j;
        if (e < rows) {
            float tmp[4];
#pragma unroll
            for (int i = 0; i < 4; ++i) tmp[i] = silu_f(acc2[j * 4 + i]);
            *(float4*)&xkd[(e0 + e) * 64 + cs * 4] = *(float4*)&tmp[0];
        }
    }
}

// ---------------------------------------------------------------------------
// triplet phase: agg[ji] += xkd[kj] * (sbf_row @ Wc_sbf). One wave per triplet.
// ---------------------------------------------------------------------------
__global__ __launch_bounds__(256) void ktrip(
        const float* __restrict__ sbf, const int* __restrict__ idx_kj,
        const int* __restrict__ idx_ji, const float* __restrict__ xkd,
        const float* __restrict__ wc_sbf, float* __restrict__ agg, int T) {
    const int lane = threadIdx.x & 63;
    float wc[42];
#pragma unroll
    for (int s = 0; s < 42; ++s) wc[s] = wc_sbf[s * 64 + lane];
    const int wave = blockIdx.x * (blockDim.x >> 6) + (threadIdx.x >> 6);
    const int nw = gridDim.x * (blockDim.x >> 6);
    for (int t = wave; t < T; t += nw) {
        const float* srow = sbf + (size_t)t * 42;
        float acc = 0.f;
#pragma unroll
        for (int q = 0; q < 21; ++q) {           // 8B-aligned loads (42*4 % 16 != 0)
            float2 v = *(const float2*)&srow[q * 2];
            acc = fmaf(v.x, wc[q * 2 + 0], acc);
            acc = fmaf(v.y, wc[q * 2 + 1], acc);
        }
        int kj = idx_kj[t];
        int ji = idx_ji[t];
        float m = xkd[(size_t)kj * 64 + lane] * acc;
        atomicAdd(&agg[(size_t)ji * 64 + lane], m);
    }
}

// ---------------------------------------------------------------------------
// post phase: h = x_ji + silu(agg@W_up); res_before; silu(h@W_lin+b)+x; res_after
// ---------------------------------------------------------------------------
__global__ __launch_bounds__(256, 2) void kedge_post(
        const float* __restrict__ x, const float* __restrict__ agg,
        const float* __restrict__ W_ji, const float* __restrict__ b_ji,
        const float* __restrict__ W_up,
        const float* __restrict__ W_rb, const float* __restrict__ b_rb,
        const float* __restrict__ W_lin, const float* __restrict__ b_lin,
        const float* __restrict__ W_ra, const float* __restrict__ b_ra,
        float* __restrict__ out, int E) {
    __shared__ float A[64 * LSTRIDE];
    __shared__ float Bt[64 * LSTRIDE];
    const int tid = threadIdx.x;
    const int es = tid >> 4, cs = tid & 15;
    const long e0 = (long)blockIdx.x * 64;
    long rem = (long)E - e0;
    const int rows = rem > 64 ? 64 : (int)rem;
    float acc[32];

    // Bt <- x_ji = silu(x@W_ji + b_ji)
    load_tile(x, A, rows, 128, e0, 128, tid);
    __syncthreads();
    mv_tile<128, 128>(W_ji, A, es, cs, acc);
    store_silu_bias(Bt, acc, b_ji, es, cs);
    __syncthreads();

    // A <- agg tile; acc = agg@W_up; A <- Bt + silu(acc)   (= h)
    load_tile(agg, A, rows, 64, e0, 64, tid);
    __syncthreads();
    mv_tile<64, 128>(W_up, A, es, cs, acc);
    __syncthreads();   // everyone done reading A before in-place overwrite
#pragma unroll
    for (int j = 0; j < 4; ++j) {
        int e = es * 4 + j;
        int cb = swzc(e, cs * 8);
        float4 v0 = *(const float4*)&Bt[e * LSTRIDE + cb];
        float4 v1 = *(const float4*)&Bt[e * LSTRIDE + cb + 4];
        float tmp[8] = {v0.x, v0.y, v0.z, v0.w, v1.x, v1.y, v1.z, v1.w};
#pragma unroll
        for (int i = 0; i < 8; ++i) tmp[i] += silu_f(acc[j * 8 + i]);
        *(float4*)&A[e * LSTRIDE + cb]     = *(float4*)&tmp[0];
        *(float4*)&A[e * LSTRIDE + cb + 4] = *(float4*)&tmp[4];
    }
    __syncthreads();

    // res_before (1 layer): Bt <- silu(A@W0+b0); A += silu(Bt@W1+b1)
    mv_tile<128, 128>(W_rb, A, es, cs, acc);
    store_silu_bias(Bt, acc, b_rb, es, cs);
    __syncthreads();
    mv_tile<128, 128>(W_rb + 16384, Bt, es, cs, acc);
    add_silu_bias(A, acc, b_rb + 128, es, cs);
    __syncthreads();

    // Bt <- silu(A@W_lin + b_lin) + x (reload from global)
    mv_tile<128, 128>(W_lin, A, es, cs, acc);
    {
        float bv[8];
#pragma unroll
        for (int i = 0; i < 8; ++i) bv[i] = b_lin[cs * 8 + i];
#pragma unroll
        for (int j = 0; j < 4; ++j) {
            int e = es * 4 + j;
            int cb = swzc(e, cs * 8);
            float xg[8] = {0.f, 0.f, 0.f, 0.f, 0.f, 0.f, 0.f, 0.f};
            if (e < rows) {
                float4 x0 = *(const float4*)&x[(e0 + e) * 128 + cs * 8];
                float4 x1 = *(const float4*)&x[(e0 + e) * 128 + cs * 8 + 4];
                xg[0] = x0.x; xg[1] = x0.y; xg[2] = x0.z; xg[3] = x0.w;
                xg[4] = x1.x; xg[5] = x1.y; xg[6] = x1.z; xg[7] = x1.w;
            }
            float tmp[8];
#pragma unroll
            for (int i = 0; i < 8; ++i) tmp[i] = silu_f(acc[j * 8 + i] + bv[i]) + xg[i];
            *(float4*)&Bt[e * LSTRIDE + cb]     = *(float4*)&tmp[0];
            *(float4*)&Bt[e * LSTRIDE + cb + 4] = *(float4*)&tmp[4];
        }
    }
    __syncthreads();

    // res_after layer 0
    mv_tile<128, 128>(W_ra, Bt, es, cs, acc);
    store_silu_bias(A, acc, b_ra, es, cs);
    __syncthreads();
    mv_tile<128, 128>(W_ra + 16384, A, es, cs, acc);
    add_silu_bias(Bt, acc, b_ra + 128, es, cs);
    __syncthreads();

    // res_after layer 1
    mv_tile<128, 128>(W_ra + 32768, Bt, es, cs, acc);
    store_silu_bias(A, acc, b_ra + 256, es, cs);
    __syncthreads();
    mv_tile<128, 128>(W_ra + 49152, A, es, cs, acc);
    add_silu_bias(Bt, acc, b_ra + 384, es, cs);
    __syncthreads();

    // out <- Bt
#pragma unroll
    for (int j = 0; j < 4; ++j) {
        int e = es * 4 + j;
        if (e < rows) {
            int cb = swzc(e, cs * 8);
            float4 v0 = *(const float4*)&Bt[e * LSTRIDE + cb];
            float4 v1 = *(const float4*)&Bt[e * LSTRIDE + cb + 4];
            *(float4*)&out[(e0 + e) * 128 + cs * 8]     = v0;
            *(float4*)&out[(e0 + e) * 128 + cs * 8 + 4] = v1;
        }
    }
}

extern "C" void kernel_launch(void* const* d_in, const int* in_sizes, int n_in,
                              void* d_out, int out_size, void* d_ws, size_t ws_size,
                              hipStream_t stream) {
    const float* x      = (const float*)d_in[0];
    const float* rbf    = (const float*)d_in[1];
    const float* sbf    = (const float*)d_in[2];
    const int*   idx_kj = (const int*)d_in[3];
    const int*   idx_ji = (const int*)d_in[4];
    const float* W_rbf1 = (const float*)d_in[5];
    const float* W_rbf2 = (const float*)d_in[6];
    const float* W_sbf1 = (const float*)d_in[7];
    const float* W_sbf2 = (const float*)d_in[8];
    const float* W_kj   = (const float*)d_in[9];
    const float* b_kj   = (const float*)d_in[10];
    const float* W_ji   = (const float*)d_in[11];
    const float* b_ji   = (const float*)d_in[12];
    const float* W_down = (const float*)d_in[13];
    const float* W_up   = (const float*)d_in[14];
    const float* W_rb   = (const float*)d_in[15];
    const float* b_rb   = (const float*)d_in[16];
    const float* W_lin  = (const float*)d_in[17];
    const float* b_lin  = (const float*)d_in[18];
    const float* W_ra   = (const float*)d_in[19];
    const float* b_ra   = (const float*)d_in[20];

    const int E = in_sizes[0] / 128;
    const int T = in_sizes[3];

    float* agg = (float*)d_ws;                  // E*64
    float* xkd = agg + (size_t)E * 64;          // E*64
    float* wcr = xkd + (size_t)E * 64;          // 768
    float* wcs = wcr + 768;                     // 2688

    kweights<<<16, 256, 0, stream>>>(W_rbf1, W_rbf2, W_sbf1, W_sbf2, wcr, wcs);
    hipMemsetAsync(agg, 0, (size_t)E * 64 * sizeof(float), stream);

    const int gE = (E + 63) / 64;
    kedge_pre<<<gE, 256, 0, stream>>>(x, rbf, W_kj, b_kj, wcr, W_down, xkd, E);
    ktrip<<<2048, 256, 0, stream>>>(sbf, idx_kj, idx_ji, xkd, wcs, agg, T);
    kedge_post<<<gE, 256, 0, stream>>>(x, agg, W_ji, b_ji, W_up, W_rb, b_rb,
                                       W_lin, b_lin, W_ra, b_ra, (float*)d_out, E);
}